// Round 1
// baseline (2800.498 us; speedup 1.0000x reference)
//
#include <hip/hip_runtime.h>
#include <math.h>

// ---------------- constants ----------------
#define B_   128
#define T_   288
#define U_   256
#define H_   4
#define HD_  64
#define MT   (B_*T_)     // 36864 rows
#define EPSF 1e-6f

typedef _Float16 h2_t __attribute__((ext_vector_type(2)));

#if defined(__has_builtin)
#  if __has_builtin(__builtin_amdgcn_fdot2)
#    define HAS_FDOT2 1
#  endif
#endif
#ifndef HAS_FDOT2
#  define HAS_FDOT2 0
#endif

// ---------------- generic tiled fp32 GEMM ----------------
// C[M,N](ldc) = alpha * A[M,K](lda) @ B[K,N](ldb)  (+ bias[N])
// TB=true: B given row-major [N,K] (i.e. compute A @ B^T)
// Batched via blockIdx.z: z1=z/zdiv, z2=z%zdiv; base += z1*s?1 + z2*s?2.
template<bool TB>
__global__ __launch_bounds__(256) void gemm_kernel(
    const float* __restrict__ A, const float* __restrict__ Bm,
    float* __restrict__ C, const float* __restrict__ bias,
    int M, int N, int K, int lda, int ldb, int ldc,
    long sA1, long sA2, long sB1, long sB2, long sC1, long sC2,
    int zdiv, float alpha)
{
  int z  = blockIdx.z;
  int z1 = z / zdiv, z2 = z - z1 * zdiv;
  A  += (long)z1*sA1 + (long)z2*sA2;
  Bm += (long)z1*sB1 + (long)z2*sB2;
  C  += (long)z1*sC1 + (long)z2*sC2;

  __shared__ float As[16][68];
  __shared__ float Bs[16][68];

  const int tid = threadIdx.x;
  const int tx  = tid & 15;     // 0..15 (n)
  const int ty  = tid >> 4;     // 0..15 (m)
  const int rowBase = blockIdx.y * 64;
  const int colBase = blockIdx.x * 64;

  float acc[4][4] = {};

  const int lr = tid >> 2;         // 0..63
  const int lk = (tid & 3) << 2;   // 0,4,8,12

  for (int k0 = 0; k0 < K; k0 += 16) {
    // A tile: [64 rows][16 k], stored transposed As[k][m]
    {
      float4 a4 = {0.f,0.f,0.f,0.f};
      int ar = rowBase + lr;
      if (ar < M) a4 = *(const float4*)(A + (long)ar*lda + k0 + lk);
      As[lk+0][lr]=a4.x; As[lk+1][lr]=a4.y; As[lk+2][lr]=a4.z; As[lk+3][lr]=a4.w;
    }
    if (TB) {
      float4 b4 = {0.f,0.f,0.f,0.f};
      int bn = colBase + lr;
      if (bn < N) b4 = *(const float4*)(Bm + (long)bn*ldb + k0 + lk);
      Bs[lk+0][lr]=b4.x; Bs[lk+1][lr]=b4.y; Bs[lk+2][lr]=b4.z; Bs[lk+3][lr]=b4.w;
    } else {
      int bk  = tid >> 4;          // 0..15
      int bn4 = (tid & 15) << 2;   // 0..60
      float4 b4 = {0.f,0.f,0.f,0.f};
      if (colBase + bn4 < N) b4 = *(const float4*)(Bm + (long)(k0+bk)*ldb + colBase + bn4);
      *(float4*)(&Bs[bk][bn4]) = b4;
    }
    __syncthreads();
    #pragma unroll
    for (int k = 0; k < 16; ++k) {
      float4 av = *(const float4*)(&As[k][ty<<2]);
      float4 bv = *(const float4*)(&Bs[k][tx<<2]);
      acc[0][0]+=av.x*bv.x; acc[0][1]+=av.x*bv.y; acc[0][2]+=av.x*bv.z; acc[0][3]+=av.x*bv.w;
      acc[1][0]+=av.y*bv.x; acc[1][1]+=av.y*bv.y; acc[1][2]+=av.y*bv.z; acc[1][3]+=av.y*bv.w;
      acc[2][0]+=av.z*bv.x; acc[2][1]+=av.z*bv.y; acc[2][2]+=av.z*bv.z; acc[2][3]+=av.z*bv.w;
      acc[3][0]+=av.w*bv.x; acc[3][1]+=av.w*bv.y; acc[3][2]+=av.w*bv.z; acc[3][3]+=av.w*bv.w;
    }
    __syncthreads();
  }

  const int cn = colBase + (tx << 2);
  if (cn < N) {
    float4 bb = {0.f,0.f,0.f,0.f};
    if (bias) bb = *(const float4*)(bias + cn);
    #pragma unroll
    for (int i = 0; i < 4; ++i) {
      int r = rowBase + (ty << 2) + i;
      if (r < M) {
        float4 v;
        v.x = acc[i][0]*alpha + bb.x;
        v.y = acc[i][1]*alpha + bb.y;
        v.z = acc[i][2]*alpha + bb.z;
        v.w = acc[i][3]*alpha + bb.w;
        *(float4*)(C + (long)r*ldc + cn) = v;
      }
    }
  }
}

// ---------------- LayerNorm over 256 cols ----------------
// out[row] = LN(in[row] (+skip_pre[row])) * s + b (+ skip_post[row])
__global__ __launch_bounds__(256) void ln256_kernel(
    const float* __restrict__ in, const float* __restrict__ skip_pre,
    const float* __restrict__ skip_post,
    const float* __restrict__ s, const float* __restrict__ b,
    float* __restrict__ out)
{
  __shared__ float sb[4];
  long row = blockIdx.x;
  int tid  = threadIdx.x;
  long idx = row*256 + tid;
  float v = in[idx];
  if (skip_pre) v += skip_pre[idx];
  float m = v;
  for (int o = 32; o; o >>= 1) m += __shfl_xor(m, o);
  if ((tid & 63) == 0) sb[tid >> 6] = m;
  __syncthreads();
  m = (sb[0]+sb[1]+sb[2]+sb[3]) * (1.f/256.f);
  __syncthreads();
  float d = v - m;
  float var = d*d;
  for (int o = 32; o; o >>= 1) var += __shfl_xor(var, o);
  if ((tid & 63) == 0) sb[tid >> 6] = var;
  __syncthreads();
  var = (sb[0]+sb[1]+sb[2]+sb[3]) * (1.f/256.f);
  float y = d * rsqrtf(var + EPSF) * s[tid] + b[tid];
  if (skip_post) y += skip_post[idx];
  out[idx] = y;
}

// ---------------- GRU scan: one workgroup per batch ----------------
// Wh held register-resident as packed f16 pairs (96 VGPRs/thread),
// fp32 accumulation via v_dot2_f32_f16. h kept fp32 (master) + f16 (dot input).
__global__ __launch_bounds__(1024, 1) void gru_scan_kernel(
    const float* __restrict__ xg,   // [B,T,768]
    const float* __restrict__ Wh,   // [256,768]
    const float* __restrict__ bhn,  // [256]
    float* __restrict__ g)          // [B,T,256]
{
  const int b   = blockIdx.x;
  const int tid = threadIdx.x;
  const int u   = tid & 255;   // unit
  const int kq  = tid >> 8;    // k-quarter (64 h values)

  __shared__ float hf[256];
  __shared__ h2_t  hh2s[128];
  __shared__ float part[4][3][256];

  h2_t wr[32], wz[32], wn[32];
  #pragma unroll
  for (int r = 0; r < 32; ++r) {
    const float* p0 = Wh + (long)(kq*64 + 2*r)*768 + u;
    const float* p1 = p0 + 768;
    h2_t a; a.x = (_Float16)p0[0];   a.y = (_Float16)p1[0];   wr[r] = a;
    h2_t c; c.x = (_Float16)p0[256]; c.y = (_Float16)p1[256]; wz[r] = c;
    h2_t d; d.x = (_Float16)p0[512]; d.y = (_Float16)p1[512]; wn[r] = d;
  }
  float bn = (kq == 0) ? bhn[u] : 0.f;
  if (tid < 256) hf[tid] = 0.f;
  if (tid < 128) { h2_t zz; zz.x = (_Float16)0.f; zz.y = (_Float16)0.f; hh2s[tid] = zz; }
  __syncthreads();

  const float* xgb = xg + (long)b*T_*768;
  float* gb = g + (long)b*T_*256;

  for (int t = 0; t < T_; ++t) {
    float xr = 0.f, xz = 0.f, xn = 0.f;
    if (kq == 0) {  // prefetch input gates; latency hidden behind dot phase
      const float* xt = xgb + (long)t*768;
      xr = xt[u]; xz = xt[u+256]; xn = xt[u+512];
    }
    float ar = 0.f, az = 0.f, an = 0.f;
    #pragma unroll
    for (int r = 0; r < 32; ++r) {
      h2_t hv = hh2s[kq*32 + r];   // wave-uniform address -> broadcast, conflict-free
#if HAS_FDOT2
      ar = __builtin_amdgcn_fdot2(hv, wr[r], ar, false);
      az = __builtin_amdgcn_fdot2(hv, wz[r], az, false);
      an = __builtin_amdgcn_fdot2(hv, wn[r], an, false);
#else
      ar += (float)hv.x*(float)wr[r].x + (float)hv.y*(float)wr[r].y;
      az += (float)hv.x*(float)wz[r].x + (float)hv.y*(float)wz[r].y;
      an += (float)hv.x*(float)wn[r].x + (float)hv.y*(float)wn[r].y;
#endif
    }
    part[kq][0][u] = ar; part[kq][1][u] = az; part[kq][2][u] = an;
    __syncthreads();
    if (kq == 0) {
      float hr = part[0][0][u]+part[1][0][u]+part[2][0][u]+part[3][0][u] + xr;
      float hz = part[0][1][u]+part[1][1][u]+part[2][1][u]+part[3][1][u] + xz;
      float hn = part[0][2][u]+part[1][2][u]+part[2][2][u]+part[3][2][u];
      float rr = 1.f / (1.f + __expf(-hr));
      float z  = 1.f / (1.f + __expf(-hz));
      float nx = xn + rr * (hn + bn);
      float e2 = __expf(2.f * nx);
      float nv = (e2 - 1.f) / (e2 + 1.f);
      float hnew = (1.f - z) * nv + z * hf[u];
      hf[u] = hnew;
      ((_Float16*)hh2s)[u] = (_Float16)hnew;
      gb[(long)t*256 + u] = hnew;
    }
    __syncthreads();
  }
}

// ---------------- softmax over 288 cols, in place ----------------
__global__ __launch_bounds__(128) void softmax288_kernel(float* __restrict__ S)
{
  __shared__ float sb[2];
  long row = blockIdx.x;
  float* p = S + row * T_;
  int tid = threadIdx.x;
  float v0 = p[tid], v1 = p[tid+128];
  float v2 = (tid < 32) ? p[tid+256] : -1e30f;
  float mx = fmaxf(fmaxf(v0, v1), v2);
  for (int o = 32; o; o >>= 1) mx = fmaxf(mx, __shfl_xor(mx, o));
  if ((tid & 63) == 0) sb[tid >> 6] = mx;
  __syncthreads();
  mx = fmaxf(sb[0], sb[1]);
  __syncthreads();
  v0 = __expf(v0 - mx);
  v1 = __expf(v1 - mx);
  v2 = (tid < 32) ? __expf(v2 - mx) : 0.f;
  float sm = v0 + v1 + v2;
  for (int o = 32; o; o >>= 1) sm += __shfl_xor(sm, o);
  if ((tid & 63) == 0) sb[tid >> 6] = sm;
  __syncthreads();
  float inv = 1.f / (sb[0] + sb[1]);
  p[tid] = v0*inv; p[tid+128] = v1*inv;
  if (tid < 32) p[tid+256] = v2*inv;
}

// ---------------- mean over T ----------------
__global__ __launch_bounds__(256) void meanT_kernel(
    const float* __restrict__ x, float* __restrict__ xm)
{
  int b = blockIdx.x, u = threadIdx.x;
  const float* p = x + (long)b*T_*U_ + u;
  float s = 0.f;
  for (int t = 0; t < T_; ++t) s += p[(long)t*U_];
  xm[b*U_ + u] = s * (1.f/(float)T_);
}

// ---------------- MLP head: one block per batch ----------------
__global__ __launch_bounds__(128) void head_kernel(
    const float* __restrict__ xm, const float* __restrict__ other,
    const float* __restrict__ m1W, const float* __restrict__ m1b,
    const float* __restrict__ l1s, const float* __restrict__ l1b,
    const float* __restrict__ m2W, const float* __restrict__ m2b,
    const float* __restrict__ l2s, const float* __restrict__ l2b,
    const float* __restrict__ oW,  const float* __restrict__ ob,
    float* __restrict__ outp)
{
  __shared__ float c[320];
  __shared__ float h1[128];
  __shared__ float sb[2];
  int b = blockIdx.x, tid = threadIdx.x;
  c[tid]       = xm[b*256 + tid];
  c[tid + 128] = xm[b*256 + tid + 128];
  if (tid < 64) c[256 + tid] = other[b*64 + tid];
  __syncthreads();
  // h1 = LN(relu(c @ m1W + m1b))
  float s = m1b[tid];
  for (int i = 0; i < 320; ++i) s += c[i] * m1W[i*128 + tid];
  s = fmaxf(s, 0.f);
  float m = s;
  for (int o = 32; o; o >>= 1) m += __shfl_xor(m, o);
  if ((tid & 63) == 0) sb[tid >> 6] = m;
  __syncthreads();
  m = (sb[0] + sb[1]) * (1.f/128.f);
  __syncthreads();
  float d = s - m, var = d*d;
  for (int o = 32; o; o >>= 1) var += __shfl_xor(var, o);
  if ((tid & 63) == 0) sb[tid >> 6] = var;
  __syncthreads();
  var = (sb[0] + sb[1]) * (1.f/128.f);
  h1[tid] = d * rsqrtf(var + EPSF) * l1s[tid] + l1b[tid];
  __syncthreads();
  // h2 = LN(relu(h1 @ m2W + m2b)), then out = h2 @ oW + ob  (wave 0 only)
  if (tid < 64) {
    float s2 = m2b[tid];
    for (int i = 0; i < 128; ++i) s2 += h1[i] * m2W[i*64 + tid];
    s2 = fmaxf(s2, 0.f);
    float m2 = s2;
    for (int o = 32; o; o >>= 1) m2 += __shfl_xor(m2, o);
    m2 *= (1.f/64.f);
    float d2 = s2 - m2, v2 = d2*d2;
    for (int o = 32; o; o >>= 1) v2 += __shfl_xor(v2, o);
    v2 *= (1.f/64.f);
    float h2v = d2 * rsqrtf(v2 + EPSF) * l2s[tid] + l2b[tid];
    float y = h2v * oW[tid];
    for (int o = 32; o; o >>= 1) y += __shfl_xor(y, o);
    if (tid == 0) outp[b] = y + ob[0];
  }
}

// ---------------- host orchestration ----------------
static inline void gemm_nn(hipStream_t st, const float* A, const float* Bm, float* C,
                           const float* bias, int M, int N, int K,
                           int lda, int ldb, int ldc, float alpha)
{
  dim3 g((N + 63)/64, (M + 63)/64, 1);
  gemm_kernel<false><<<g, 256, 0, st>>>(A, Bm, C, bias, M, N, K, lda, ldb, ldc,
                                        0,0,0,0,0,0, 1, alpha);
}

extern "C" void kernel_launch(void* const* d_in, const int* in_sizes, int n_in,
                              void* d_out, int out_size, void* d_ws, size_t ws_size,
                              hipStream_t stream)
{
  const float* cgm   = (const float*)d_in[0];
  const float* other = (const float*)d_in[1];
  const float* d0_W  = (const float*)d_in[2];
  const float* d0_b  = (const float*)d_in[3];
  const float* ln0_s = (const float*)d_in[4];
  const float* ln0_b = (const float*)d_in[5];
  const float* gWi   = (const float*)d_in[6];
  const float* gbi   = (const float*)d_in[7];
  const float* gWh   = (const float*)d_in[8];
  const float* gbhn  = (const float*)d_in[9];
  const float* ln1_s = (const float*)d_in[10];
  const float* ln1_b = (const float*)d_in[11];
  const float* Wq    = (const float*)d_in[12];
  const float* bq    = (const float*)d_in[13];
  const float* Wk    = (const float*)d_in[14];
  const float* bk    = (const float*)d_in[15];
  const float* Wv    = (const float*)d_in[16];
  const float* bv    = (const float*)d_in[17];
  const float* Wo    = (const float*)d_in[18];
  const float* bo    = (const float*)d_in[19];
  const float* ln2_s = (const float*)d_in[20];
  const float* ln2_b = (const float*)d_in[21];
  const float* m1W   = (const float*)d_in[22];
  const float* m1b   = (const float*)d_in[23];
  const float* l1s   = (const float*)d_in[24];
  const float* l1b   = (const float*)d_in[25];
  const float* m2W   = (const float*)d_in[26];
  const float* m2b   = (const float*)d_in[27];
  const float* l2s   = (const float*)d_in[28];
  const float* l2b   = (const float*)d_in[29];
  const float* oW    = (const float*)d_in[30];
  const float* ob    = (const float*)d_in[31];
  float* out = (float*)d_out;

  // workspace layout (floats); total ~231 MB
  float* ws    = (float*)d_ws;
  float* big   = ws;                  // 28,311,552  (xg, later qkv, later wo tmp)
  float* x     = big  + 28311552;     //  9,437,184
  float* go    = x    +  9437184;     //  9,437,184  (gru out, later attn out)
  float* Sbuf  = go   +  9437184;     // 10,616,832  (scores, 32-batch chunk)
  float* xmean = Sbuf + 10616832;     //     32,768
  (void)ws_size; (void)in_sizes; (void)n_in; (void)out_size;

  // x = LN(cgm @ d0_W + d0_b)
  gemm_nn(stream, cgm, d0_W, big, d0_b, MT, 256, 16, 16, 256, 256, 1.f);
  ln256_kernel<<<MT, 256, 0, stream>>>(big, nullptr, nullptr, ln0_s, ln0_b, x);

  for (int i = 0; i < 2; ++i) {
    const float* Wi_i = gWi + (long)i*196608;
    const float* Wh_i = gWh + (long)i*196608;

    // xg = x @ Wi + bi
    gemm_nn(stream, x, Wi_i, big, gbi + i*768, MT, 768, 256, 256, 768, 768, 1.f);
    // GRU scan
    gru_scan_kernel<<<128, 1024, 0, stream>>>(big, Wh_i, gbhn + i*256, go);
    // x = LN(g) + x
    ln256_kernel<<<MT, 256, 0, stream>>>(go, nullptr, x, ln1_s + i*256, ln1_b + i*256, x);

    // qkv into big: row layout [q(256) | k(256) | v(256)]
    gemm_nn(stream, x, Wq + (long)i*65536, big,       bq + i*256, MT, 256, 256, 256, 256, 768, 1.f);
    gemm_nn(stream, x, Wk + (long)i*65536, big + 256, bk + i*256, MT, 256, 256, 256, 256, 768, 1.f);
    gemm_nn(stream, x, Wv + (long)i*65536, big + 512, bv + i*256, MT, 256, 256, 256, 256, 768, 1.f);

    // attention in 4 chunks of 32 batches (S buffer = 42.5 MB)
    for (int cb = 0; cb < 4; ++cb) {
      const float* qb = big + (long)cb*32*T_*768;
      {
        dim3 g(5, 5, 128);   // z = local_b*4 + head
        gemm_kernel<true><<<g, 256, 0, stream>>>(
            qb, qb + 256, Sbuf, nullptr,
            T_, T_, 64, 768, 768, T_,
            (long)T_*768, 64, (long)T_*768, 64, (long)4*T_*T_, (long)T_*T_,
            4, 0.125f);
      }
      softmax288_kernel<<<32*4*T_, 128, 0, stream>>>(Sbuf);
      {
        dim3 g(1, 5, 128);
        gemm_kernel<false><<<g, 256, 0, stream>>>(
            Sbuf, qb + 512, go + (long)cb*32*T_*256, nullptr,
            T_, 64, T_, T_, 768, 256,
            (long)4*T_*T_, (long)T_*T_, (long)T_*768, 64, (long)T_*256, 64,
            4, 1.f);
      }
    }

    // a = o @ Wo + bo ; x = LN(a + x)
    gemm_nn(stream, go, Wo + (long)i*65536, big, bo + i*256, MT, 256, 256, 256, 256, 256, 1.f);
    ln256_kernel<<<MT, 256, 0, stream>>>(big, x, nullptr, ln2_s + i*256, ln2_b + i*256, x);
  }

  meanT_kernel<<<128, 256, 0, stream>>>(x, xmean);
  head_kernel<<<128, 128, 0, stream>>>(xmean, other, m1W, m1b, l1s, l1b,
                                       m2W, m2b, l2s, l2b, oW, ob, out);
}